// Round 6
// baseline (305.521 us; speedup 1.0000x reference)
//
#include <hip/hip_runtime.h>
#include <cstdint>
#include <cstddef>

#define NF 256   // features
#define NG 512   // hidden (2F)
#define NC 64    // classes
#define NB 8192  // batch
#define NK 16    // active rules
#define BT 64    // fs batch tile
#define SM 264   // mv LDS row stride (shorts)
#define SC 136   // cb LDS row stride (shorts): 272 B rows, 16-B aligned
#define CW 128   // h1 chunk width (cols)

typedef __attribute__((ext_vector_type(8))) short short8;
typedef __attribute__((ext_vector_type(4))) float floatx4;

// round-half-up bf16 pair pack: low short = a, high short = b
__device__ __forceinline__ unsigned int packbf2(float a, float b) {
    unsigned int ua = __float_as_uint(a), ub = __float_as_uint(b);
    return ((ua + 0x8000u) >> 16) | ((ub + 0x8000u) & 0xffff0000u);
}
__device__ __forceinline__ float elu1(float z) {
    return z > 0.0f ? z : (__expf(z) - 1.0f);
}

// ---------------- kernel 0: weights fp32 -> bf16 (vectorized x4) ----------------
// layout (ushort elements): [0,131072) W1b | [131072,262144) W2b | [262144,786432) Wcb
__global__ __launch_bounds__(256) void conv_kernel(
    const float* __restrict__ W1, const float* __restrict__ W2,
    const float* __restrict__ Wc, unsigned short* __restrict__ wb)
{
    int i = (blockIdx.x * 256 + threadIdx.x) * 4;
    if (i >= 786432) return;
    const float* src; int off;
    if (i < 131072)      { src = W1; off = i; }
    else if (i < 262144) { src = W2; off = i - 131072; }
    else                 { src = Wc; off = i - 262144; }
    const float4 v = *(const float4*)(src + off);
    uint2 pk;
    pk.x = packbf2(v.x, v.y);
    pk.y = packbf2(v.z, v.w);
    *(uint2*)(wb + i) = pk;
}

// ---------------- kernel 1: fused membership -> MLP -> fsi (pipelined chunks) ----------------
// grid: 2048 blocks = 16 rules x 128 batch tiles; 512 threads (8 waves).
// h1 chunked at 128 cols, cb DOUBLE-BUFFERED; each barrier interval fuses
// phase2(c-1) [LDS-fed MFMA -> persistent acc2] with phase1(c) [global-fed
// MFMA -> acc1]: two independent chains per wave so LDS waits hide behind
// global-fed MFMAs and vice versa (R2..R5 were phase-serialized: pipe-cycle
// sum == wall). Phase1 is transposed (A=W1) with 2x2 outer product ->
// LDS/MFMA = 0.5 and vector b64 ELU stores (R3-verified mapping).
// LDS: mv 64x264 (33.8K) + 2x cb 64x136 (17.4K each) = 68.6 KB -> 2 blocks/CU.
__global__ __launch_bounds__(512, 4) void fs_kernel(
    const float* __restrict__ x, const float* __restrict__ proto,
    const float* __restrict__ var, const unsigned short* __restrict__ W1b,
    const float* __restrict__ b1, const unsigned short* __restrict__ W2b,
    const float* __restrict__ b2, const float* __restrict__ W3,
    const float* __restrict__ b3, const int* __restrict__ ridx,
    float* __restrict__ fsi)
{
    extern __shared__ unsigned short smem[];
    unsigned short* mv  = smem;                       // [64][SM]
    unsigned short* cb0 = smem + 64 * SM;             // [64][SC]
    unsigned short* cb1 = cb0 + 64 * SC;              // [64][SC]

    const int t    = threadIdx.x;
    const int kidx = blockIdx.x & 15;
    const int tile = blockIdx.x >> 4;
    const int r    = ridx[kidx];
    const int b0   = tile * BT;

    // ---- phase 0: mv = exp(-(x-p)^2 / (2 v^2)), v=clip(var,1e-4,0.1) ----
    {
        const int col   = (t & 63) * 4;
        const int rbase = t >> 6;           // 0..7
        const float4 p4 = *(const float4*)(proto + (size_t)r * NF + col);
        float4 v4 = *(const float4*)(var + (size_t)r * NF + col);
        float cx = fminf(fmaxf(v4.x, 1e-4f), 0.1f);
        float cy = fminf(fmaxf(v4.y, 1e-4f), 0.1f);
        float cz = fminf(fmaxf(v4.z, 1e-4f), 0.1f);
        float cw = fminf(fmaxf(v4.w, 1e-4f), 0.1f);
        float ix = 0.5f / (cx * cx), iy = 0.5f / (cy * cy);
        float iz = 0.5f / (cz * cz), iw = 0.5f / (cw * cw);
#pragma unroll
        for (int i = 0; i < 8; ++i) {
            int row = i * 8 + rbase;
            const float4 xv = *(const float4*)(x + (size_t)(b0 + row) * NF + col);
            float dx = xv.x - p4.x, dy = xv.y - p4.y, dz = xv.z - p4.z, dw = xv.w - p4.w;
            uint2 pk;
            pk.x = packbf2(__expf(-dx * dx * ix), __expf(-dy * dy * iy));
            pk.y = packbf2(__expf(-dz * dz * iz), __expf(-dw * dw * iw));
            *(uint2*)(mv + row * SM + col) = pk;
        }
    }
    __syncthreads();

    const int wave = t >> 6, lane = t & 63;
    const int ln = lane & 15, lq = lane >> 4;
    const int wm = wave & 3;      // n_out 32-group within chunk
    const int wg = wave >> 2;     // batch half for phase1

    // persistent h2 accumulator: batch 64 (4 m-frags) x n2 32 (2 n-frags)
    floatx4 acc2[4][2];
#pragma unroll
    for (int mt = 0; mt < 4; ++mt)
#pragma unroll
        for (int nt = 0; nt < 2; ++nt) {
            floatx4 z = {0.0f, 0.0f, 0.0f, 0.0f};
            acc2[mt][nt] = z;
        }

    const int mvrow0 = (wg * 32 + ln) * SM;
    const int mvrow1 = (wg * 32 + 16 + ln) * SM;

    // ---- interval 0: phase1(0) -> cb0 ----
    {
        floatx4 acc1[2][2];
#pragma unroll
        for (int a = 0; a < 2; ++a)
#pragma unroll
            for (int b = 0; b < 2; ++b) {
                floatx4 z = {0.0f, 0.0f, 0.0f, 0.0f};
                acc1[a][b] = z;
            }
        const unsigned short* wA = W1b + (size_t)(wm * 32 + ln) * NF + lq * 8;
#pragma unroll
        for (int k0 = 0; k0 < 8; ++k0) {
            short8 a0 = *(const short8*)(wA + k0 * 32);
            short8 a1 = *(const short8*)(wA + 16 * NF + k0 * 32);
            short8 bm0 = *(const short8*)(mv + mvrow0 + k0 * 32 + lq * 8);
            short8 bm1 = *(const short8*)(mv + mvrow1 + k0 * 32 + lq * 8);
            acc1[0][0] = __builtin_amdgcn_mfma_f32_16x16x32_bf16(a0, bm0, acc1[0][0], 0, 0, 0);
            acc1[0][1] = __builtin_amdgcn_mfma_f32_16x16x32_bf16(a0, bm1, acc1[0][1], 0, 0, 0);
            acc1[1][0] = __builtin_amdgcn_mfma_f32_16x16x32_bf16(a1, bm0, acc1[1][0], 0, 0, 0);
            acc1[1][1] = __builtin_amdgcn_mfma_f32_16x16x32_bf16(a1, bm1, acc1[1][1], 0, 0, 0);
        }
        // ELU store (transposed D: reg axis = n_out, contiguous -> b64)
#pragma unroll
        for (int a = 0; a < 2; ++a) {
            const int coln = wm * 32 + a * 16 + lq * 4;
            const float4 bias = *(const float4*)(b1 + coln);
#pragma unroll
            for (int b = 0; b < 2; ++b) {
                const int row = wg * 32 + b * 16 + ln;
                uint2 pk;
                pk.x = packbf2(elu1(acc1[a][b][0] + bias.x), elu1(acc1[a][b][1] + bias.y));
                pk.y = packbf2(elu1(acc1[a][b][2] + bias.z), elu1(acc1[a][b][3] + bias.w));
                *(uint2*)(cb0 + row * SC + coln) = pk;
            }
        }
    }
    __syncthreads();

    // ---- intervals c=1..3: fused phase2(c-1) + phase1(c) ----
    for (int c = 1; c < 4; ++c) {
        unsigned short* cbw       = (c & 1) ? cb1 : cb0;
        const unsigned short* cbr = (c & 1) ? cb0 : cb1;
        floatx4 acc1[2][2];
#pragma unroll
        for (int a = 0; a < 2; ++a)
#pragma unroll
            for (int b = 0; b < 2; ++b) {
                floatx4 z = {0.0f, 0.0f, 0.0f, 0.0f};
                acc1[a][b] = z;
            }
        const unsigned short* wA  = W1b + (size_t)(c * CW + wm * 32 + ln) * NF + lq * 8;
        const unsigned short* wB2 = W2b + (size_t)(wave * 32 + ln) * NG + (c - 1) * CW + lq * 8;
#pragma unroll
        for (int i = 0; i < 4; ++i) {
            // phase2(c-1), kstep i: LDS-fed chain into acc2
            short8 bf0 = *(const short8*)(wB2 + i * 32);
            short8 bf1 = *(const short8*)(wB2 + (size_t)16 * NG + i * 32);
            short8 am[4];
#pragma unroll
            for (int mt = 0; mt < 4; ++mt)
                am[mt] = *(const short8*)(cbr + (mt * 16 + ln) * SC + i * 32 + lq * 8);
            // phase1(c), ksteps 2i, 2i+1: global-fed chain into acc1
            short8 a0 = *(const short8*)(wA + (2 * i) * 32);
            short8 a1 = *(const short8*)(wA + 16 * NF + (2 * i) * 32);
            short8 bm0 = *(const short8*)(mv + mvrow0 + (2 * i) * 32 + lq * 8);
            short8 bm1 = *(const short8*)(mv + mvrow1 + (2 * i) * 32 + lq * 8);
            short8 a2 = *(const short8*)(wA + (2 * i + 1) * 32);
            short8 a3 = *(const short8*)(wA + 16 * NF + (2 * i + 1) * 32);
            short8 bm2 = *(const short8*)(mv + mvrow0 + (2 * i + 1) * 32 + lq * 8);
            short8 bm3 = *(const short8*)(mv + mvrow1 + (2 * i + 1) * 32 + lq * 8);
#pragma unroll
            for (int mt = 0; mt < 4; ++mt) {
                acc2[mt][0] = __builtin_amdgcn_mfma_f32_16x16x32_bf16(am[mt], bf0, acc2[mt][0], 0, 0, 0);
                acc2[mt][1] = __builtin_amdgcn_mfma_f32_16x16x32_bf16(am[mt], bf1, acc2[mt][1], 0, 0, 0);
            }
            acc1[0][0] = __builtin_amdgcn_mfma_f32_16x16x32_bf16(a0, bm0, acc1[0][0], 0, 0, 0);
            acc1[0][1] = __builtin_amdgcn_mfma_f32_16x16x32_bf16(a0, bm1, acc1[0][1], 0, 0, 0);
            acc1[1][0] = __builtin_amdgcn_mfma_f32_16x16x32_bf16(a1, bm0, acc1[1][0], 0, 0, 0);
            acc1[1][1] = __builtin_amdgcn_mfma_f32_16x16x32_bf16(a1, bm1, acc1[1][1], 0, 0, 0);
            acc1[0][0] = __builtin_amdgcn_mfma_f32_16x16x32_bf16(a2, bm2, acc1[0][0], 0, 0, 0);
            acc1[0][1] = __builtin_amdgcn_mfma_f32_16x16x32_bf16(a2, bm3, acc1[0][1], 0, 0, 0);
            acc1[1][0] = __builtin_amdgcn_mfma_f32_16x16x32_bf16(a3, bm2, acc1[1][0], 0, 0, 0);
            acc1[1][1] = __builtin_amdgcn_mfma_f32_16x16x32_bf16(a3, bm3, acc1[1][1], 0, 0, 0);
        }
        // ELU store chunk c -> cbw (disjoint from cbr; one barrier per interval)
#pragma unroll
        for (int a = 0; a < 2; ++a) {
            const int coln = wm * 32 + a * 16 + lq * 4;
            const float4 bias = *(const float4*)(b1 + c * CW + coln);
#pragma unroll
            for (int b = 0; b < 2; ++b) {
                const int row = wg * 32 + b * 16 + ln;
                uint2 pk;
                pk.x = packbf2(elu1(acc1[a][b][0] + bias.x), elu1(acc1[a][b][1] + bias.y));
                pk.y = packbf2(elu1(acc1[a][b][2] + bias.z), elu1(acc1[a][b][3] + bias.w));
                *(uint2*)(cbw + row * SC + coln) = pk;
            }
        }
        __syncthreads();
    }

    // ---- tail: phase2(3) on cb1 ----
    {
        const unsigned short* wB2 = W2b + (size_t)(wave * 32 + ln) * NG + 3 * CW + lq * 8;
#pragma unroll
        for (int i = 0; i < 4; ++i) {
            short8 bf0 = *(const short8*)(wB2 + i * 32);
            short8 bf1 = *(const short8*)(wB2 + (size_t)16 * NG + i * 32);
            short8 am[4];
#pragma unroll
            for (int mt = 0; mt < 4; ++mt)
                am[mt] = *(const short8*)(cb1 + (mt * 16 + ln) * SC + i * 32 + lq * 8);
#pragma unroll
            for (int mt = 0; mt < 4; ++mt) {
                acc2[mt][0] = __builtin_amdgcn_mfma_f32_16x16x32_bf16(am[mt], bf0, acc2[mt][0], 0, 0, 0);
                acc2[mt][1] = __builtin_amdgcn_mfma_f32_16x16x32_bf16(am[mt], bf1, acc2[mt][1], 0, 0, 0);
            }
        }
    }

    // ---- phase 3: fsi[b] = ELU(h2)[b,:] . W3 + b3 ----
    // part[] lives in cb0 region: cb0 last read in interval 3 (before its
    // end barrier); tail reads cb1 only -> disjoint, safe without a barrier.
    float* part = (float*)cb0;
    float bb[2], ww[2];
#pragma unroll
    for (int nt = 0; nt < 2; ++nt) {
        int n = wave * 32 + nt * 16 + ln;
        bb[nt] = b2[n];
        ww[nt] = W3[n];
    }
#pragma unroll
    for (int mt = 0; mt < 4; ++mt)
#pragma unroll
        for (int rg = 0; rg < 4; ++rg) {
            float s = elu1(acc2[mt][0][rg] + bb[0]) * ww[0]
                    + elu1(acc2[mt][1][rg] + bb[1]) * ww[1];
            s += __shfl_xor(s, 1);
            s += __shfl_xor(s, 2);
            s += __shfl_xor(s, 4);
            s += __shfl_xor(s, 8);
            if (ln == 0) part[wave * 64 + mt * 16 + lq * 4 + rg] = s;
        }
    __syncthreads();
    if (t < 64) {
        float s = b3[0];
#pragma unroll
        for (int w = 0; w < 8; ++w) s += part[w * 64 + t];
        fsi[(size_t)kidx * NB + b0 + t] = s;
    }
}

// ---------------- kernel 2: softmax over rules + consequent + weighted sum ----------------
// grid: 1024 blocks x 128 threads; block = 16 batch rows x 32-class half.
__global__ __launch_bounds__(128, 2) void cons_kernel(
    const float* __restrict__ x, const unsigned short* __restrict__ Wcb,
    const float* __restrict__ bc, const float* __restrict__ fsi,
    const int* __restrict__ ridx, float* __restrict__ outp,
    float* __restrict__ fire_out)
{
    __shared__ unsigned short xl[16 * SM];
    __shared__ float fire[NK][16];     // [rule][row]

    const int t  = threadIdx.x;
    const int rt = blockIdx.x >> 1;    // row tile
    const int ch = blockIdx.x & 1;     // col half
    const int b0 = rt * 16;

    // x -> bf16 LDS (16 rows)
    {
        const int col   = (t & 63) * 4;
        const int rbase = t >> 6;   // 0..1
#pragma unroll
        for (int i = 0; i < 8; ++i) {
            int row = i * 2 + rbase;
            const float4 xv = *(const float4*)(x + (size_t)(b0 + row) * NF + col);
            uint2 pk;
            pk.x = packbf2(xv.x, xv.y);
            pk.y = packbf2(xv.z, xv.w);
            *(uint2*)(xl + row * SM + col) = pk;
        }
    }
    // softmax over 16 rules: 256 items with 128 threads
#pragma unroll
    for (int h = 0; h < 2; ++h) {
        const int j = t + h * 128;
        const int row = j >> 4, k = j & 15;
        float v = fsi[(size_t)k * NB + b0 + row];
        float mx = v;
        mx = fmaxf(mx, __shfl_xor(mx, 1));
        mx = fmaxf(mx, __shfl_xor(mx, 2));
        mx = fmaxf(mx, __shfl_xor(mx, 4));
        mx = fmaxf(mx, __shfl_xor(mx, 8));
        float e = __expf(v - mx);
        float sum = e;
        sum += __shfl_xor(sum, 1);
        sum += __shfl_xor(sum, 2);
        sum += __shfl_xor(sum, 4);
        sum += __shfl_xor(sum, 8);
        float fv = e / sum;
        fire[k][row] = fv;
        if (ch == 0) fire_out[(size_t)b0 * NK + j] = fv;
    }
    __syncthreads();

    const int wave = t >> 6, lane = t & 63;
    const int ln = lane & 15, lq = lane >> 4;
    const int nb = ch * 32 + wave * 16;

    short8 afr[8];
#pragma unroll
    for (int k0i = 0; k0i < 8; ++k0i)
        afr[k0i] = *(const short8*)(xl + ln * SM + k0i * 32 + lq * 8);

    int rbase[NK];
#pragma unroll
    for (int k = 0; k < NK; ++k) rbase[k] = ridx[k] * (NC * NF);
    const int lofs = (nb + ln) * NF + lq * 8;

    floatx4 acc[NK];
#pragma unroll
    for (int k = 0; k < NK; ++k) {
        floatx4 z = {0.0f, 0.0f, 0.0f, 0.0f};
        acc[k] = z;
    }
#pragma unroll
    for (int k0i = 0; k0i < 8; ++k0i) {
        const short8 a = afr[k0i];
#pragma unroll
        for (int k = 0; k < NK; ++k) {
            short8 b = *(const short8*)(Wcb + rbase[k] + lofs + k0i * 32);
            acc[k] = __builtin_amdgcn_mfma_f32_16x16x32_bf16(a, b, acc[k], 0, 0, 0);
        }
    }

    floatx4 oacc = {0.0f, 0.0f, 0.0f, 0.0f};
#pragma unroll
    for (int k = 0; k < NK; ++k) {
        float bias = bc[(size_t)ridx[k] * NC + nb + ln];
        const float4 fv = *(const float4*)(&fire[k][lq * 4]);
        oacc[0] += fmaxf(acc[k][0] + bias, 0.0f) * fv.x;
        oacc[1] += fmaxf(acc[k][1] + bias, 0.0f) * fv.y;
        oacc[2] += fmaxf(acc[k][2] + bias, 0.0f) * fv.z;
        oacc[3] += fmaxf(acc[k][3] + bias, 0.0f) * fv.w;
    }
#pragma unroll
    for (int rg = 0; rg < 4; ++rg)
        outp[(size_t)(b0 + lq * 4 + rg) * NC + nb + ln] = oacc[rg];
}

extern "C" void kernel_launch(void* const* d_in, const int* in_sizes, int n_in,
                              void* d_out, int out_size, void* d_ws, size_t ws_size,
                              hipStream_t stream)
{
    (void)in_sizes; (void)n_in; (void)out_size;
    if (ws_size < 2097152) return;  // 1.5MB bf16 weights + 0.5MB fsi

    const float* x     = (const float*)d_in[0];
    const float* proto = (const float*)d_in[1];
    const float* var   = (const float*)d_in[2];
    const float* W1    = (const float*)d_in[3];
    const float* b1    = (const float*)d_in[4];
    const float* W2    = (const float*)d_in[5];
    const float* b2    = (const float*)d_in[6];
    const float* W3    = (const float*)d_in[7];
    const float* b3    = (const float*)d_in[8];
    const float* Wc    = (const float*)d_in[9];
    const float* bc    = (const float*)d_in[10];
    const int*   ridx  = (const int*)d_in[11];

    unsigned short* wb  = (unsigned short*)d_ws;
    unsigned short* W1b = wb;                 // 131072
    unsigned short* W2b = wb + 131072;        // 131072
    unsigned short* Wcb = wb + 262144;        // 524288
    float* fsi = (float*)((char*)d_ws + (size_t)786432 * 2);  // 16*8192 floats

    float* outp     = (float*)d_out;
    float* fire_out = outp + (size_t)NB * NC;

    conv_kernel<<<768, 256, 0, stream>>>(W1, W2, Wc, wb);

    const int fs_lds = 64 * SM * 2 + 2 * 64 * SC * 2;  // 33792 + 34816 = 68608 B
    hipFuncSetAttribute((const void*)fs_kernel,
                        hipFuncAttributeMaxDynamicSharedMemorySize, fs_lds);
    fs_kernel<<<2048, 512, fs_lds, stream>>>(x, proto, var, W1b, b1, W2b, b2,
                                             W3, b3, ridx, fsi);
    cons_kernel<<<1024, 128, 0, stream>>>(x, Wcb, bc, fsi, ridx, outp, fire_out);
}

// Round 7
// 256.496 us; speedup vs baseline: 1.1911x; 1.1911x over previous
//
#include <hip/hip_runtime.h>
#include <cstdint>
#include <cstddef>

#define NF 256   // features
#define NG 512   // hidden (2F)
#define NC 64    // classes
#define NB 8192  // batch
#define NK 16    // active rules
#define BT 64    // fs batch tile

typedef __attribute__((ext_vector_type(8))) short short8;
typedef __attribute__((ext_vector_type(4))) float floatx4;

__device__ __forceinline__ unsigned short f2bf(float f) {
    union { float f; unsigned int u; } a; a.f = f;
    unsigned int u = a.u;
    u += 0x7fffu + ((u >> 16) & 1u);   // RNE
    return (unsigned short)(u >> 16);
}
__device__ __forceinline__ unsigned int packbf2(float a, float b) {
    unsigned int ua = __float_as_uint(a), ub = __float_as_uint(b);
    return ((ua + 0x8000u) >> 16) | ((ub + 0x8000u) & 0xffff0000u);
}
__device__ __forceinline__ float elu1(float z) {
    return z > 0.0f ? z : (__expf(z) - 1.0f);
}

// ---------------- kernel 0: weights fp32 -> bf16 (vectorized x4) ----------------
// layout (ushort elements): [0,131072) W1b | [131072,262144) W2b | [262144,786432) Wcb
__global__ __launch_bounds__(256) void conv_kernel(
    const float* __restrict__ W1, const float* __restrict__ W2,
    const float* __restrict__ Wc, unsigned short* __restrict__ wb)
{
    int i = (blockIdx.x * 256 + threadIdx.x) * 4;
    if (i >= 786432) return;
    const float* src; int off;
    if (i < 131072)      { src = W1; off = i; }
    else if (i < 262144) { src = W2; off = i - 131072; }
    else                 { src = Wc; off = i - 262144; }
    const float4 v = *(const float4*)(src + off);
    uint2 pk;
    pk.x = packbf2(v.x, v.y);
    pk.y = packbf2(v.z, v.w);
    *(uint2*)(wb + i) = pk;
}

// ---------------- kernel 1: fused membership -> MLP -> fsi ----------------
// EXACT R2 structure (measured best of 6 variants: 159 us; R3..R6 all 160-212).
// grid: 2048 blocks = 16 rules x 128 batch tiles; 512 threads (8 waves).
// LDS: mv [64][264] + cb [64][264] = 67584 B -> 2 blocks/CU.
__global__ __launch_bounds__(512, 4) void fs_kernel(
    const float* __restrict__ x, const float* __restrict__ proto,
    const float* __restrict__ var, const unsigned short* __restrict__ W1b,
    const float* __restrict__ b1, const unsigned short* __restrict__ W2b,
    const float* __restrict__ b2, const float* __restrict__ W3,
    const float* __restrict__ b3, const int* __restrict__ ridx,
    float* __restrict__ fsi)
{
    extern __shared__ unsigned short smem[];
    unsigned short* mv = smem;              // [64][264]
    unsigned short* cb = smem + 64 * 264;   // [64][264] chunk buffer / part[]

    const int t    = threadIdx.x;
    const int kidx = blockIdx.x & 15;
    const int tile = blockIdx.x >> 4;
    const int r    = ridx[kidx];
    const int b0   = tile * BT;

    // ---- phase 0: mv = exp(-(x-p)^2 / (2 v^2)), v=clip(var,1e-4,0.1) ----
    {
        const int col   = (t & 63) * 4;
        const int rbase = t >> 6;           // 0..7
        const float4 p4 = *(const float4*)(proto + (size_t)r * NF + col);
        float4 v4 = *(const float4*)(var + (size_t)r * NF + col);
        float cx = fminf(fmaxf(v4.x, 1e-4f), 0.1f);
        float cy = fminf(fmaxf(v4.y, 1e-4f), 0.1f);
        float cz = fminf(fmaxf(v4.z, 1e-4f), 0.1f);
        float cw = fminf(fmaxf(v4.w, 1e-4f), 0.1f);
        float ix = 0.5f / (cx * cx), iy = 0.5f / (cy * cy);
        float iz = 0.5f / (cz * cz), iw = 0.5f / (cw * cw);
#pragma unroll
        for (int i = 0; i < 8; ++i) {
            int row = i * 8 + rbase;
            const float4 xv = *(const float4*)(x + (size_t)(b0 + row) * NF + col);
            float dx = xv.x - p4.x, dy = xv.y - p4.y, dz = xv.z - p4.z, dw = xv.w - p4.w;
            union { unsigned short s[4]; uint2 v; } pk;
            pk.s[0] = f2bf(__expf(-dx * dx * ix));
            pk.s[1] = f2bf(__expf(-dy * dy * iy));
            pk.s[2] = f2bf(__expf(-dz * dz * iz));
            pk.s[3] = f2bf(__expf(-dw * dw * iw));
            *(uint2*)(mv + row * 264 + col) = pk.v;
        }
    }
    __syncthreads();

    const int wave = t >> 6, lane = t & 63;
    const int ln = lane & 15, lq = lane >> 4;

    // persistent h2 accumulator: wave n2-tile = 32 cols
    floatx4 acc2[4][2];
#pragma unroll
    for (int mi = 0; mi < 4; ++mi)
#pragma unroll
        for (int ni = 0; ni < 2; ++ni) {
            floatx4 z = {0.0f, 0.0f, 0.0f, 0.0f};
            acc2[mi][ni] = z;
        }

    for (int c = 0; c < 2; ++c) {
        // ---- phase 1 (chunk c): h1 cols [c*256, c*256+256) ----
        floatx4 acc1[4][2];
#pragma unroll
        for (int mi = 0; mi < 4; ++mi)
#pragma unroll
            for (int ni = 0; ni < 2; ++ni) {
                floatx4 z = {0.0f, 0.0f, 0.0f, 0.0f};
                acc1[mi][ni] = z;
            }
        const int nbase = c * 256 + wave * 32;
#pragma unroll
        for (int k0 = 0; k0 < NF; k0 += 32) {
            short8 a[4];
#pragma unroll
            for (int mi = 0; mi < 4; ++mi)
                a[mi] = *(const short8*)(mv + (mi * 16 + ln) * 264 + k0 + lq * 8);
#pragma unroll
            for (int ni = 0; ni < 2; ++ni) {
                short8 b = *(const short8*)(W1b + (size_t)(nbase + ni * 16 + ln) * NF + k0 + lq * 8);
#pragma unroll
                for (int mi = 0; mi < 4; ++mi)
                    acc1[mi][ni] = __builtin_amdgcn_mfma_f32_16x16x32_bf16(a[mi], b, acc1[mi][ni], 0, 0, 0);
            }
        }
        __syncthreads();   // prior chunk's phase-2 reads of cb are done
        // ELU + bias, write chunk to LDS (chunk-local col = wave*32 + ni*16 + ln)
#pragma unroll
        for (int ni = 0; ni < 2; ++ni) {
            int n = nbase + ni * 16 + ln;
            float bias = b1[n];
            int ccol = wave * 32 + ni * 16 + ln;
#pragma unroll
            for (int mi = 0; mi < 4; ++mi)
#pragma unroll
                for (int rg = 0; rg < 4; ++rg) {
                    float z = acc1[mi][ni][rg] + bias;
                    cb[(mi * 16 + lq * 4 + rg) * 264 + ccol] = f2bf(elu1(z));
                }
        }
        __syncthreads();
        // ---- phase 2 (chunk c): acc2 += cb @ W2[:, c*256 : c*256+256]^T ----
#pragma unroll
        for (int k0 = 0; k0 < 256; k0 += 32) {
            short8 a[4];
#pragma unroll
            for (int mi = 0; mi < 4; ++mi)
                a[mi] = *(const short8*)(cb + (mi * 16 + ln) * 264 + k0 + lq * 8);
#pragma unroll
            for (int ni = 0; ni < 2; ++ni) {
                short8 b = *(const short8*)(W2b + (size_t)(wave * 32 + ni * 16 + ln) * NG + c * 256 + k0 + lq * 8);
#pragma unroll
                for (int mi = 0; mi < 4; ++mi)
                    acc2[mi][ni] = __builtin_amdgcn_mfma_f32_16x16x32_bf16(a[mi], b, acc2[mi][ni], 0, 0, 0);
            }
        }
    }

    // ---- phase 3: fsi[b] = ELU(h2)[b,:] . W3 + b3 ----
    __syncthreads();                 // reuse cb as float part[8][64]
    float* part = (float*)cb;
    float bb[2], ww[2];
#pragma unroll
    for (int ni = 0; ni < 2; ++ni) {
        int n = wave * 32 + ni * 16 + ln;
        bb[ni] = b2[n];
        ww[ni] = W3[n];
    }
#pragma unroll
    for (int mi = 0; mi < 4; ++mi)
#pragma unroll
        for (int rg = 0; rg < 4; ++rg) {
            float s = elu1(acc2[mi][0][rg] + bb[0]) * ww[0]
                    + elu1(acc2[mi][1][rg] + bb[1]) * ww[1];
            s += __shfl_xor(s, 1);
            s += __shfl_xor(s, 2);
            s += __shfl_xor(s, 4);
            s += __shfl_xor(s, 8);
            if (ln == 0) part[wave * 64 + mi * 16 + lq * 4 + rg] = s;
        }
    __syncthreads();
    if (t < 64) {
        float s = b3[0];
#pragma unroll
        for (int w = 0; w < 8; ++w) s += part[w * 64 + t];
        fsi[(size_t)kidx * NB + b0 + t] = s;
    }
}

// ---------------- kernel 2: softmax + consequent + weighted sum ----------------
// grid: 1024 blocks x 128 threads; block = 32 batch rows x 16-class group
// (R5 was 16 rows x 32 cols: 256 MB Wc L2-traffic; this halves it to 128 MB
// and doubles x amortization). 4 blocks/CU; per kstep 16 INDEPENDENT rule
// loads feed 16 independent MFMA chains.
__global__ __launch_bounds__(128, 2) void cons_kernel(
    const float* __restrict__ x, const unsigned short* __restrict__ Wcb,
    const float* __restrict__ bc, const float* __restrict__ fsi,
    const int* __restrict__ ridx, float* __restrict__ outp,
    float* __restrict__ fire_out)
{
    __shared__ unsigned short xl[32 * 264];
    __shared__ float fire[NK][32];     // [rule][row]

    const int t  = threadIdx.x;
    const int rt = blockIdx.x >> 2;    // row tile (0..255)
    const int cg = blockIdx.x & 3;     // col group (16 classes)
    const int b0 = rt * 32;

    // x -> bf16 LDS (32 rows; 128 threads: 2 rows/pass, 16 passes)
    {
        const int col   = (t & 63) * 4;
        const int rbase = t >> 6;   // 0..1
#pragma unroll
        for (int i = 0; i < 16; ++i) {
            int row = i * 2 + rbase;
            const float4 xv = *(const float4*)(x + (size_t)(b0 + row) * NF + col);
            uint2 pk;
            pk.x = packbf2(xv.x, xv.y);
            pk.y = packbf2(xv.z, xv.w);
            *(uint2*)(xl + row * 264 + col) = pk;
        }
    }
    // softmax over 16 rules: 512 items with 128 threads (4 per thread)
#pragma unroll
    for (int h = 0; h < 4; ++h) {
        const int j = t + h * 128;
        const int row = j >> 4, k = j & 15;
        float v = fsi[(size_t)k * NB + b0 + row];
        float mx = v;
        mx = fmaxf(mx, __shfl_xor(mx, 1));
        mx = fmaxf(mx, __shfl_xor(mx, 2));
        mx = fmaxf(mx, __shfl_xor(mx, 4));
        mx = fmaxf(mx, __shfl_xor(mx, 8));
        float e = __expf(v - mx);
        float sum = e;
        sum += __shfl_xor(sum, 1);
        sum += __shfl_xor(sum, 2);
        sum += __shfl_xor(sum, 4);
        sum += __shfl_xor(sum, 8);
        float fv = e / sum;
        fire[k][row] = fv;
        if (cg == 0) fire_out[(size_t)b0 * NK + j] = fv;
    }
    __syncthreads();

    const int wave = t >> 6, lane = t & 63;
    const int ln = lane & 15, lq = lane >> 4;
    const int mrow = wave * 16;        // wave's 16 batch rows
    const int nb   = cg * 16;          // block's 16 classes

    // x fragments register-cached, reused across all 16 rules
    short8 afr[8];
#pragma unroll
    for (int k0i = 0; k0i < 8; ++k0i)
        afr[k0i] = *(const short8*)(xl + (mrow + ln) * 264 + k0i * 32 + lq * 8);

    int rbase[NK];
#pragma unroll
    for (int k = 0; k < NK; ++k) rbase[k] = ridx[k] * (NC * NF);
    const int lofs = (nb + ln) * NF + lq * 8;

    floatx4 acc[NK];
#pragma unroll
    for (int k = 0; k < NK; ++k) {
        floatx4 z = {0.0f, 0.0f, 0.0f, 0.0f};
        acc[k] = z;
    }
#pragma unroll
    for (int k0i = 0; k0i < 8; ++k0i) {
        const short8 a = afr[k0i];
#pragma unroll
        for (int k = 0; k < NK; ++k) {
            short8 b = *(const short8*)(Wcb + rbase[k] + lofs + k0i * 32);
            acc[k] = __builtin_amdgcn_mfma_f32_16x16x32_bf16(a, b, acc[k], 0, 0, 0);
        }
    }

    floatx4 oacc = {0.0f, 0.0f, 0.0f, 0.0f};
#pragma unroll
    for (int k = 0; k < NK; ++k) {
        float bias = bc[(size_t)ridx[k] * NC + nb + ln];
        const float4 fv = *(const float4*)(&fire[k][mrow + lq * 4]);
        oacc[0] += fmaxf(acc[k][0] + bias, 0.0f) * fv.x;
        oacc[1] += fmaxf(acc[k][1] + bias, 0.0f) * fv.y;
        oacc[2] += fmaxf(acc[k][2] + bias, 0.0f) * fv.z;
        oacc[3] += fmaxf(acc[k][3] + bias, 0.0f) * fv.w;
    }
#pragma unroll
    for (int rg = 0; rg < 4; ++rg)
        outp[(size_t)(b0 + mrow + lq * 4 + rg) * NC + nb + ln] = oacc[rg];
}

extern "C" void kernel_launch(void* const* d_in, const int* in_sizes, int n_in,
                              void* d_out, int out_size, void* d_ws, size_t ws_size,
                              hipStream_t stream)
{
    (void)in_sizes; (void)n_in; (void)out_size;
    if (ws_size < 2097152) return;  // 1.5MB bf16 weights + 0.5MB fsi

    const float* x     = (const float*)d_in[0];
    const float* proto = (const float*)d_in[1];
    const float* var   = (const float*)d_in[2];
    const float* W1    = (const float*)d_in[3];
    const float* b1    = (const float*)d_in[4];
    const float* W2    = (const float*)d_in[5];
    const float* b2    = (const float*)d_in[6];
    const float* W3    = (const float*)d_in[7];
    const float* b3    = (const float*)d_in[8];
    const float* Wc    = (const float*)d_in[9];
    const float* bc    = (const float*)d_in[10];
    const int*   ridx  = (const int*)d_in[11];

    unsigned short* wb  = (unsigned short*)d_ws;
    unsigned short* W1b = wb;                 // 131072
    unsigned short* W2b = wb + 131072;        // 131072
    unsigned short* Wcb = wb + 262144;        // 524288
    float* fsi = (float*)((char*)d_ws + (size_t)786432 * 2);  // 16*8192 floats

    float* outp     = (float*)d_out;
    float* fire_out = outp + (size_t)NB * NC;

    conv_kernel<<<768, 256, 0, stream>>>(W1, W2, Wc, wb);

    const int fs_lds = 2 * 64 * 264 * 2;  // 67584 B
    hipFuncSetAttribute((const void*)fs_kernel,
                        hipFuncAttributeMaxDynamicSharedMemorySize, fs_lds);
    fs_kernel<<<2048, 512, fs_lds, stream>>>(x, proto, var, W1b, b1, W2b, b2,
                                             W3, b3, ridx, fsi);
    cons_kernel<<<1024, 128, 0, stream>>>(x, Wcb, bc, fsi, ridx, outp, fire_out);
}